// Round 1
// baseline (43.906 us; speedup 1.0000x reference)
//
#include <hip/hip_runtime.h>

#define N 8192

// ---------------------------------------------------------------------------
// Kernel A: per-block stats of l = ||x_i||  ->  partials[b] = {sum, sumsq, min, max}
// ---------------------------------------------------------------------------
__global__ __launch_bounds__(256) void stats_kernel(const float* __restrict__ x,
                                                    float4* __restrict__ partials) {
    const int tid = blockIdx.x * 256 + threadIdx.x;   // grid 32*256 == N exactly
    float2 xv = reinterpret_cast<const float2*>(x)[tid];
    float l = sqrtf(xv.x * xv.x + xv.y * xv.y);

    __shared__ float4 red[256];
    red[threadIdx.x] = make_float4(l, l * l, l, l);
    __syncthreads();
    for (int s = 128; s > 0; s >>= 1) {
        if (threadIdx.x < s) {
            float4 a = red[threadIdx.x], b = red[threadIdx.x + s];
            red[threadIdx.x] = make_float4(a.x + b.x, a.y + b.y,
                                           fminf(a.z, b.z), fmaxf(a.w, b.w));
        }
        __syncthreads();
    }
    if (threadIdx.x == 0) partials[blockIdx.x] = red[0];
}

// ---------------------------------------------------------------------------
// Kernel B: reduce 32 partials (double precision), compute
//   t    = mean + 0.1 * std(ddof=1)   (the mask threshold)
//   lmin, lmax (global, for the analytic row-max bound)
// ---------------------------------------------------------------------------
__global__ void finalize_kernel(const float4* __restrict__ partials,
                                float4* __restrict__ scal) {
    if (threadIdx.x == 0 && blockIdx.x == 0) {
        double sum = 0.0, sumsq = 0.0;
        float mn = 3.0e38f, mx = -3.0e38f;
        for (int i = 0; i < 32; ++i) {
            float4 p = partials[i];
            sum += (double)p.x;
            sumsq += (double)p.y;
            mn = fminf(mn, p.z);
            mx = fmaxf(mx, p.w);
        }
        double mean = sum / (double)N;
        double var  = (sumsq - sum * sum / (double)N) / (double)(N - 1);
        float t = (float)(mean + 0.1 * sqrt(var));
        scal[0] = make_float4(t, mn, mx, 0.0f);
    }
}

// ---------------------------------------------------------------------------
// Kernel C: streaming masked softmax-attention.
//   512 blocks x 512 threads (8 waves). Each block caches {l, angle} for all
//   N keys in LDS (64 KiB) and computes 16 rows (2 rows per wave).
//   Row max replaced by the analytic upper bound 0.5*max((li-lmin)^2,(li-lmax)^2)
//   (softmax is shift-invariant; all unmasked exponents stay in [-~15, 0]).
//   Everything folded into exp2 domain: w = 2^( K*d*d + c ), K = 0.5*log2(e),
//   c = -M (unmasked) or -1e9*log2(e) - M (masked -> exp2 flushes to 0).
// ---------------------------------------------------------------------------
__global__ __launch_bounds__(512, 4) void attn_kernel(const float* __restrict__ x,
                                                      const float4* __restrict__ scal,
                                                      float2* __restrict__ out) {
    __shared__ float2 la[N];  // 64 KiB: {l, angle}

    const float4 sc = scal[0];
    const float t = sc.x, lmin = sc.y, lmax = sc.z;

    for (int j = threadIdx.x; j < N; j += 512) {
        float2 xv = reinterpret_cast<const float2*>(x)[j];
        float l = sqrtf(xv.x * xv.x + xv.y * xv.y);
        float ang = atan2f(xv.y, xv.x);
        la[j] = make_float2(l, ang);
    }
    __syncthreads();

    const int wave = threadIdx.x >> 6;
    const int lane = threadIdx.x & 63;
    const float K = 0.72134752044f;  // 0.5 * log2(e)

    for (int rr = 0; rr < 2; ++rr) {
        const int i = blockIdx.x * 16 + wave * 2 + rr;
        const float li = la[i].x;

        const float d1 = li - lmin, d2 = li - lmax;
        const float M  = fmaxf(d1 * d1, d2 * d2) * K;    // upper bound (log2 domain)
        const float cu = -M;
        const float cm = -1.0e9f * 1.44269504f - M;      // masked: exp2 -> 0

        float e0 = 0.f, e1 = 0.f, a0 = 0.f, a1 = 0.f;
#pragma unroll 4
        for (int j = lane; j < N; j += 128) {
            float2 v0 = la[j];
            float2 v1 = la[j + 64];
            float dd0 = li - v0.x;
            float dd1 = li - v1.x;
            float s0 = fmaf(dd0 * dd0, K, (v0.x < t) ? cm : cu);
            float s1 = fmaf(dd1 * dd1, K, (v1.x < t) ? cm : cu);
            float w0 = exp2f(s0);
            float w1 = exp2f(s1);
            e0 += w0;
            e1 += w1;
            a0 = fmaf(w0, v0.y, a0);
            a1 = fmaf(w1, v1.y, a1);
        }
        float e = e0 + e1, a = a0 + a1;
#pragma unroll
        for (int off = 32; off > 0; off >>= 1) {
            e += __shfl_xor(e, off, 64);
            a += __shfl_xor(a, off, 64);
        }
        if (lane == 0) {
            float oa = a / e;
            out[i] = make_float2(li * cosf(oa), li * sinf(oa));
        }
    }
}

// ---------------------------------------------------------------------------
extern "C" void kernel_launch(void* const* d_in, const int* in_sizes, int n_in,
                              void* d_out, int out_size, void* d_ws, size_t ws_size,
                              hipStream_t stream) {
    const float* x = (const float*)d_in[0];
    // d_in[1] (w) unused in the trainable=False path.
    float4* partials = (float4*)d_ws;     // 32 * 16 B
    float4* scal     = partials + 32;     // 16 B

    stats_kernel<<<32, 256, 0, stream>>>(x, partials);
    finalize_kernel<<<1, 64, 0, stream>>>(partials, scal);
    attn_kernel<<<512, 512, 0, stream>>>(x, scal, (float2*)d_out);
}

// Round 2
// 25.140 us; speedup vs baseline: 1.7465x; 1.7465x over previous
//
#include <hip/hip_runtime.h>

#define N 8192
#define KLOG2E 0.7213475108f   // 0.5 * log2(e)

// ---------------------------------------------------------------------------
// Prep kernel: one block, 1024 threads.
//  1. l = ||x||, block-wide stats -> t = mean + 0.1*std(ddof=1), lmax
//  2. deterministic compaction of unmasked keys (l >= t) -> {l, atan2} in ws
//     (masked keys have weight exactly 0: score -1e9 vs unmasked max >= 0)
//  3. pad to multiple of 128 with {l=t, a=0} sentinels (weight corrected
//     analytically in attn epilogue: npad * 2^(K(li-t)^2 - M))
// ---------------------------------------------------------------------------
__global__ __launch_bounds__(1024) void prep_kernel(const float* __restrict__ x,
                                                    float* __restrict__ hdrf,
                                                    int* __restrict__ hdri,
                                                    float2* __restrict__ keys) {
    const int tid = threadIdx.x;
    const int lane = tid & 63, wave = tid >> 6;   // 16 waves

    float2 xv[8]; float l[8];
#pragma unroll
    for (int k = 0; k < 8; ++k) {
        xv[k] = reinterpret_cast<const float2*>(x)[tid + k * 1024];
        l[k] = sqrtf(xv[k].x * xv[k].x + xv[k].y * xv[k].y);
    }
    float s = 0.f, s2 = 0.f, mn = 3e38f, mx = -3e38f;
#pragma unroll
    for (int k = 0; k < 8; ++k) {
        s += l[k]; s2 += l[k] * l[k];
        mn = fminf(mn, l[k]); mx = fmaxf(mx, l[k]);
    }
    for (int o = 32; o > 0; o >>= 1) {
        s  += __shfl_xor(s, o, 64);
        s2 += __shfl_xor(s2, o, 64);
        mn = fminf(mn, __shfl_xor(mn, o, 64));
        mx = fmaxf(mx, __shfl_xor(mx, o, 64));
    }
    __shared__ float4 wred[16];
    __shared__ float bc[2];
    if (lane == 0) wred[wave] = make_float4(s, s2, mn, mx);
    __syncthreads();
    if (tid == 0) {
        double S = 0.0, S2 = 0.0; float MX = -3e38f;
        for (int i = 0; i < 16; ++i) {
            float4 p = wred[i];
            S += (double)p.x; S2 += (double)p.y; MX = fmaxf(MX, p.w);
        }
        double mean = S / (double)N;
        double var  = (S2 - S * S / (double)N) / (double)(N - 1);
        float t = (float)(mean + 0.1 * sqrt(var));
        bc[0] = t; bc[1] = MX;
        hdrf[0] = t; hdrf[1] = MX;
    }
    __syncthreads();
    const float t = bc[0];

    // flags + exclusive scan for deterministic compaction
    int cnt = 0; bool f[8];
#pragma unroll
    for (int k = 0; k < 8; ++k) { f[k] = (l[k] >= t); cnt += f[k] ? 1 : 0; }
    int inc = cnt;
    for (int o = 1; o < 64; o <<= 1) {
        int v = __shfl_up(inc, o, 64);
        if (lane >= o) inc += v;
    }
    __shared__ int wcnt[16];
    if (lane == 63) wcnt[wave] = inc;
    __syncthreads();
    int wbase = 0, M = 0;
    for (int i = 0; i < 16; ++i) { if (i < wave) wbase += wcnt[i]; M += wcnt[i]; }
    int pos = wbase + inc - cnt;
    if (M == 0) {   // degenerate fallback: constant -1e9 cancels -> all keys live
        pos = tid * 8; M = N;
#pragma unroll
        for (int k = 0; k < 8; ++k) f[k] = true;
    }
#pragma unroll
    for (int k = 0; k < 8; ++k)
        if (f[k]) keys[pos++] = make_float2(l[k], atan2f(xv[k].y, xv[k].x));

    const int Mpad = (M + 127) & ~127;
    const int npad = Mpad - M;
    if (tid < npad) keys[M + tid] = make_float2(t, 0.f);
    if (tid == 0) { hdri[0] = Mpad; hdri[1] = npad; }
}

// ---------------------------------------------------------------------------
// Attn kernel: 512 blocks x 512 threads (8 waves, 2 rows/wave).
// Compacted keys staged in LDS; inner loop reads key PAIRS via ds_read_b128
// (stride 16 B = conflict-free full-BW pattern). Per key: 5 VALU + 1 exp2.
// Row max replaced by analytic bound M = K*max((li-t)^2, (lmax-li)^2)
// (valid since unmasked keys lie in [t, lmax]; softmax shift-invariant).
// ---------------------------------------------------------------------------
__global__ __launch_bounds__(512) void attn_kernel(const float* __restrict__ x,
                                                   const float* __restrict__ hdrf,
                                                   const int* __restrict__ hdri,
                                                   const float2* __restrict__ keysv,
                                                   float2* __restrict__ out) {
    __shared__ float4 kk[N / 2];   // 64 KiB worst case
    __shared__ float rowl[16];
    const int tid = threadIdx.x;
    const float t = hdrf[0], lmax = hdrf[1];
    const int Mpad = hdri[0], npad = hdri[1];
    const int P = Mpad >> 1;       // float4 count (multiple of 64)

    const float4* kf4 = reinterpret_cast<const float4*>(keysv);
    for (int p = tid; p < P; p += 512) kk[p] = kf4[p];
    if (tid < 16) {
        float2 xv = reinterpret_cast<const float2*>(x)[blockIdx.x * 16 + tid];
        rowl[tid] = sqrtf(xv.x * xv.x + xv.y * xv.y);
    }
    __syncthreads();

    const int wave = tid >> 6, lane = tid & 63;
#pragma unroll
    for (int rr = 0; rr < 2; ++rr) {
        const int il = wave * 2 + rr;
        const float li = rowl[il];
        const float d1 = li - t, d2 = lmax - li;
        const float Mb = fmaxf(d1 * d1, d2 * d2) * KLOG2E;
        const float cu = -Mb;

        float e0 = 0.f, e1 = 0.f, a0 = 0.f, a1 = 0.f;
#pragma unroll 2
        for (int p = lane; p < P; p += 64) {
            float4 v = kk[p];                    // keys 2p, 2p+1: {l0,a0,l1,a1}
            float dd0 = li - v.x;
            float s0 = fmaf(dd0 * dd0, KLOG2E, cu);
            float w0 = exp2f(s0);
            e0 += w0; a0 = fmaf(w0, v.y, a0);
            float dd1 = li - v.z;
            float s1 = fmaf(dd1 * dd1, KLOG2E, cu);
            float w1 = exp2f(s1);
            e1 += w1; a1 = fmaf(w1, v.w, a1);
        }
        float e = e0 + e1, a = a0 + a1;
        for (int o = 32; o > 0; o >>= 1) {
            e += __shfl_xor(e, o, 64);
            a += __shfl_xor(a, o, 64);
        }
        if (lane == 0) {
            float wp = exp2f(fmaf(d1 * d1, KLOG2E, cu));   // sentinel weight
            e -= (float)npad * wp;
            float oa = a / e;
            const int i = blockIdx.x * 16 + il;
            out[i] = make_float2(li * cosf(oa), li * sinf(oa));
        }
    }
}

// ---------------------------------------------------------------------------
extern "C" void kernel_launch(void* const* d_in, const int* in_sizes, int n_in,
                              void* d_out, int out_size, void* d_ws, size_t ws_size,
                              hipStream_t stream) {
    const float* x = (const float*)d_in[0];
    float*  hdrf = (float*)d_ws;                       // 2 floats
    int*    hdri = (int*)((char*)d_ws + 64);           // 2 ints
    float2* keys = (float2*)((char*)d_ws + 256);       // up to 64 KiB

    prep_kernel<<<1, 1024, 0, stream>>>(x, hdrf, hdri, keys);
    attn_kernel<<<512, 512, 0, stream>>>(x, hdrf, hdri, keys, (float2*)d_out);
}

// Round 3
// 23.694 us; speedup vs baseline: 1.8531x; 1.0610x over previous
//
#include <hip/hip_runtime.h>

#define N 8192
#define NT 512
#define KPT (N / NT)              // 16 keys per thread
#define RPB 32                    // rows per block  -> grid = 256
#define RPW 4                     // rows per wave (8 waves * 4 = 32)
#define KLOG2E 0.7213475108f      // 0.5 * log2(e)

// ---------------------------------------------------------------------------
// Single fused kernel. 256 blocks x 512 threads; block b owns rows
// [32b, 32b+32). Each block redundantly (and deterministically) computes:
//   1. l = ||x|| for all N (16 coalesced float2 loads/thread)
//   2. block-reduce stats -> t = mean + 0.1*std(ddof=1), lmax, lmin
//      (f32 tree partials + double combine; identical order in every block)
//   3. compaction of unmasked keys (l >= t) -> {l, atan2} in LDS via block
//      scan; masked keys have weight exactly 0 (score -1e9 vs max >= 0).
//      Pad to x128 with {l=t, a=0} sentinels, corrected analytically later.
//   4. stream: 4 rows per wave SHARE each ds_read_b128 (2 keys); per key:
//      sub, fma, exp2, add, fma. Row max replaced by analytic bound
//      Mb = K*max((li-t)^2, (lmax-li)^2)  (unmasked keys lie in [t, lmax];
//      softmax is shift-invariant, exponents in [-Mb, 0], no under/overflow).
// ---------------------------------------------------------------------------
__global__ __launch_bounds__(NT) void sofa_kernel(const float* __restrict__ x,
                                                  float2* __restrict__ out) {
    __shared__ float2 keys[N];        // 64 KiB worst case
    __shared__ float4 wred[8];
    __shared__ int    wcnt[8];
    __shared__ float  rowl[RPB];
    __shared__ float  tc[3];          // t, lmax, lmin

    const int tid  = threadIdx.x;
    const int lane = tid & 63, wave = tid >> 6;
    const int rowbase = blockIdx.x * RPB;

    // ---- phase 1: load x, compute l --------------------------------------
    float2 xv[KPT]; float l[KPT];
#pragma unroll
    for (int k = 0; k < KPT; ++k)
        xv[k] = reinterpret_cast<const float2*>(x)[tid + k * NT];
#pragma unroll
    for (int k = 0; k < KPT; ++k)
        l[k] = sqrtf(xv[k].x * xv[k].x + xv[k].y * xv[k].y);

#pragma unroll
    for (int k = 0; k < KPT; ++k) {
        int rel = tid + k * NT - rowbase;
        if ((unsigned)rel < (unsigned)RPB) rowl[rel] = l[k];
    }

    // ---- phase 2: stats --------------------------------------------------
    float s = 0.f, s2 = 0.f, mx = -3e38f, mn = 3e38f;
#pragma unroll
    for (int k = 0; k < KPT; ++k) {
        s += l[k]; s2 += l[k] * l[k];
        mx = fmaxf(mx, l[k]); mn = fminf(mn, l[k]);
    }
#pragma unroll
    for (int o = 32; o > 0; o >>= 1) {
        s  += __shfl_xor(s, o, 64);
        s2 += __shfl_xor(s2, o, 64);
        mx  = fmaxf(mx, __shfl_xor(mx, o, 64));
        mn  = fminf(mn, __shfl_xor(mn, o, 64));
    }
    if (lane == 0) wred[wave] = make_float4(s, s2, mx, mn);
    __syncthreads();
    if (tid == 0) {
        double S = 0.0, S2 = 0.0; float MX = -3e38f, MN = 3e38f;
        for (int i = 0; i < 8; ++i) {
            float4 p = wred[i];
            S += (double)p.x; S2 += (double)p.y;
            MX = fmaxf(MX, p.z); MN = fminf(MN, p.w);
        }
        double mean = S / (double)N;
        double var  = (S2 - S * S / (double)N) / (double)(N - 1);
        tc[0] = (float)(mean + 0.1 * sqrt(var));
        tc[1] = MX; tc[2] = MN;
    }
    __syncthreads();
    const float t = tc[0], lmax = tc[1], lmin = tc[2];

    // ---- phase 3: flags + block scan + compact to LDS --------------------
    bool f[KPT]; int cnt = 0;
#pragma unroll
    for (int k = 0; k < KPT; ++k) { f[k] = (l[k] >= t); cnt += f[k] ? 1 : 0; }
    int inc = cnt;
#pragma unroll
    for (int o = 1; o < 64; o <<= 1) {
        int v = __shfl_up(inc, o, 64);
        if (lane >= o) inc += v;
    }
    if (lane == 63) wcnt[wave] = inc;
    __syncthreads();
    int wbase = 0, M = 0;
#pragma unroll
    for (int i = 0; i < 8; ++i) { int c = wcnt[i]; if (i < wave) wbase += c; M += c; }
    int pos = wbase + inc - cnt;
    const bool all = (M == 0);        // degenerate: -1e9 on every column cancels
    if (all) { pos = tid * KPT; M = N; }
#pragma unroll
    for (int k = 0; k < KPT; ++k)
        if (f[k] | all) keys[pos++] = make_float2(l[k], atan2f(xv[k].y, xv[k].x));
    const int Mpad = (M + 127) & ~127;
    const int npad = Mpad - M;
    if (tid < npad) keys[M + tid] = make_float2(t, 0.f);
    __syncthreads();

    // ---- phase 4: stream, 4 rows per wave share each b128 ----------------
    const float lo = all ? lmin : t;  // lower edge of live-key range
    const int P = Mpad >> 1;          // float4 count, multiple of 64
    const float4* kk = reinterpret_cast<const float4*>(keys);

    float li[RPW], cu[RPW], d1[RPW];
#pragma unroll
    for (int r = 0; r < RPW; ++r) {
        li[r] = rowl[wave * RPW + r];
        float a1 = li[r] - lo, a2 = lmax - li[r];
        cu[r] = -fmaxf(a1 * a1, a2 * a2) * KLOG2E;
        d1[r] = li[r] - t;
    }
    float ea[RPW][2] = {}, aa[RPW][2] = {};
#pragma unroll 2
    for (int p = lane; p < P; p += 64) {
        float4 v = kk[p];
#pragma unroll
        for (int r = 0; r < RPW; ++r) {
            float dd0 = li[r] - v.x;
            float w0 = exp2f(fmaf(dd0 * dd0, KLOG2E, cu[r]));
            ea[r][0] += w0; aa[r][0] = fmaf(w0, v.y, aa[r][0]);
            float dd1 = li[r] - v.z;
            float w1 = exp2f(fmaf(dd1 * dd1, KLOG2E, cu[r]));
            ea[r][1] += w1; aa[r][1] = fmaf(w1, v.w, aa[r][1]);
        }
    }

    // ---- epilogue --------------------------------------------------------
#pragma unroll
    for (int r = 0; r < RPW; ++r) {
        float e = ea[r][0] + ea[r][1], a = aa[r][0] + aa[r][1];
#pragma unroll
        for (int o = 32; o > 0; o >>= 1) {
            e += __shfl_xor(e, o, 64);
            a += __shfl_xor(a, o, 64);
        }
        if (lane == 0) {
            if (npad) {  // remove sentinel contribution (angle 0 -> only e)
                float wp = exp2f(fmaf(d1[r] * d1[r], KLOG2E, cu[r]));
                e -= (float)npad * wp;
            }
            float oa = a / e;
            int gi = rowbase + wave * RPW + r;
            out[gi] = make_float2(li[r] * cosf(oa), li[r] * sinf(oa));
        }
    }
}

// ---------------------------------------------------------------------------
extern "C" void kernel_launch(void* const* d_in, const int* in_sizes, int n_in,
                              void* d_out, int out_size, void* d_ws, size_t ws_size,
                              hipStream_t stream) {
    const float* x = (const float*)d_in[0];
    sofa_kernel<<<N / RPB, NT, 0, stream>>>(x, (float2*)d_out);
}

// Round 4
// 16.846 us; speedup vs baseline: 2.6064x; 1.4065x over previous
//
#include <hip/hip_runtime.h>

#define N 8192
#define NT 1024
#define KPT (N / NT)              // 8 keys per thread
#define RPB 32                    // rows per block -> grid = 256
#define KLOG2E 0.7213475108f      // 0.5 * log2(e)

// Branchless atan2, max err ~1.4e-6 rad (output slack is 7.9e-2).
__device__ __forceinline__ float fast_atan2f(float y, float x) {
    float ax = fabsf(x), ay = fabsf(y);
    float mx = fmaxf(ax, ay), mn = fminf(ax, ay);
    float r = mn * __builtin_amdgcn_rcpf(mx);
    float s = r * r;
    float p = fmaf(s, -0.01172120f, 0.05265332f);
    p = fmaf(s, p, -0.11643287f);
    p = fmaf(s, p, 0.19354346f);
    p = fmaf(s, p, -0.33262347f);
    p = fmaf(s, p, 0.99997726f);
    p = p * r;                                   // atan(mn/mx) in [0, pi/4]
    p = (ay > ax) ? (1.5707963268f - p) : p;
    p = (x < 0.f) ? (3.1415926536f - p) : p;
    p = copysignf(p, y);
    return (mx == 0.f) ? 0.f : p;
}

// ---------------------------------------------------------------------------
// One fused kernel, 256 blocks x 1024 threads (16 waves, 4/SIMD).
// Factorized softmax weights: for unmasked keys,
//   exp(0.5 (li-lj)^2) = 2^(K li^2) * 2^(K lj^2 - 2K li lj),  K = log2(e)/2.
// The per-row factor cancels in a/e -> compute only the scaled weight
//   w~ = exp2( fma(B_r, lj, C_j) ),  B_r = -2K li,  C_j = K lj^2,
// exponents bounded by +-K*lmax^2 (~+-13): no max bound, no over/underflow.
// Masked keys (l < t) have true weight exactly 0 -> compacted away.
// Waves 0-7 stream key-half 0, waves 8-15 half 1 (4 rows each); per-row
// partials combined through LDS.
// ---------------------------------------------------------------------------
__global__ __launch_bounds__(NT) void sofa_kernel(const float* __restrict__ x,
                                                  float2* __restrict__ out) {
    __shared__ float2 keys[N];        // 64 KiB worst case
    __shared__ float2 wred[16];
    __shared__ int    wcnt[16];
    __shared__ float  rowl[RPB];
    __shared__ float2 pred[16][4];    // per-wave row partials {e, a}
    __shared__ float  tc[1];          // threshold t

    const int tid  = threadIdx.x;
    const int lane = tid & 63, wave = tid >> 6;
    const int rowbase = blockIdx.x * RPB;

    // ---- phase 1: load x, compute l --------------------------------------
    float2 xv[KPT]; float l[KPT];
#pragma unroll
    for (int k = 0; k < KPT; ++k)
        xv[k] = reinterpret_cast<const float2*>(x)[tid + k * NT];
#pragma unroll
    for (int k = 0; k < KPT; ++k)
        l[k] = sqrtf(xv[k].x * xv[k].x + xv[k].y * xv[k].y);
#pragma unroll
    for (int k = 0; k < KPT; ++k) {
        int rel = tid + k * NT - rowbase;
        if ((unsigned)rel < (unsigned)RPB) rowl[rel] = l[k];
    }

    // ---- phase 2: stats -> t = mean + 0.1*std(ddof=1) --------------------
    float s = 0.f, s2 = 0.f;
#pragma unroll
    for (int k = 0; k < KPT; ++k) { s += l[k]; s2 += l[k] * l[k]; }
#pragma unroll
    for (int o = 32; o > 0; o >>= 1) {
        s  += __shfl_xor(s, o, 64);
        s2 += __shfl_xor(s2, o, 64);
    }
    if (lane == 0) wred[wave] = make_float2(s, s2);
    __syncthreads();
    if (tid == 0) {
        double S = 0.0, S2 = 0.0;
        for (int i = 0; i < 16; ++i) { S += (double)wred[i].x; S2 += (double)wred[i].y; }
        double mean = S / (double)N;
        double var  = (S2 - S * S / (double)N) / (double)(N - 1);
        tc[0] = (float)(mean + 0.1 * sqrt(var));
    }
    __syncthreads();
    const float t = tc[0];

    // ---- phase 3: flags + block scan + compact to LDS --------------------
    bool f[KPT]; int cnt = 0;
#pragma unroll
    for (int k = 0; k < KPT; ++k) { f[k] = (l[k] >= t); cnt += f[k] ? 1 : 0; }
    int inc = cnt;
#pragma unroll
    for (int o = 1; o < 64; o <<= 1) {
        int v = __shfl_up(inc, o, 64);
        if (lane >= o) inc += v;
    }
    if (lane == 63) wcnt[wave] = inc;
    __syncthreads();
    int wbase = 0, M = 0;
#pragma unroll
    for (int i = 0; i < 16; ++i) { int c = wcnt[i]; if (i < wave) wbase += c; M += c; }
    int pos = wbase + inc - cnt;
    const bool all = (M == 0);        // degenerate: -1e9 everywhere cancels
    if (all) { pos = tid * KPT; M = N; }
#pragma unroll
    for (int k = 0; k < KPT; ++k)
        if (f[k] | all) keys[pos++] = make_float2(l[k], fast_atan2f(xv[k].y, xv[k].x));
    const int Mpad = (M + 255) & ~255;
    const int npad = Mpad - M;
    if (tid < npad) keys[M + tid] = make_float2(t, 0.f);
    __syncthreads();

    // ---- phase 4: stream; wave-half splits keys, 4 rows share each b128 --
    const int half = wave >> 3, rg = wave & 7;
    const int P = Mpad >> 1;          // float4 count, multiple of 128
    const int Ph = P >> 1;            // per-half, multiple of 64 -> balanced
    const int base = half * Ph;
    const float4* kk = reinterpret_cast<const float4*>(keys);

    float li4[4], B4[4];
#pragma unroll
    for (int r = 0; r < 4; ++r) {
        li4[r] = rowl[rg * 4 + r];
        B4[r]  = -2.f * KLOG2E * li4[r];
    }
    float ea[4][2] = {}, aa[4][2] = {};
#pragma unroll 2
    for (int p = base + lane; p < base + Ph; p += 64) {
        float4 v = kk[p];             // keys 2p, 2p+1: {l0,a0,l1,a1}
        float C0 = (v.x * KLOG2E) * v.x;
        float C1 = (v.z * KLOG2E) * v.z;
#pragma unroll
        for (int r = 0; r < 4; ++r) {
            float w0 = __builtin_amdgcn_exp2f(fmaf(B4[r], v.x, C0));
            ea[r][0] += w0; aa[r][0] = fmaf(w0, v.y, aa[r][0]);
            float w1 = __builtin_amdgcn_exp2f(fmaf(B4[r], v.z, C1));
            ea[r][1] += w1; aa[r][1] = fmaf(w1, v.w, aa[r][1]);
        }
    }
#pragma unroll
    for (int r = 0; r < 4; ++r) {
        float e = ea[r][0] + ea[r][1], a = aa[r][0] + aa[r][1];
#pragma unroll
        for (int o = 32; o > 0; o >>= 1) {
            e += __shfl_xor(e, o, 64);
            a += __shfl_xor(a, o, 64);
        }
        if (lane == 0) pred[wave][r] = make_float2(e, a);
    }
    __syncthreads();

    // ---- epilogue: combine halves, sentinel fix, write -------------------
    if (tid < RPB) {
        int rg2 = tid >> 2, r2 = tid & 3;
        float e = pred[rg2][r2].x + pred[rg2 + 8][r2].x;
        float a = pred[rg2][r2].y + pred[rg2 + 8][r2].y;
        float li = rowl[tid];
        if (npad) {   // sentinel keys {l=t, angle=0} contribute only to e
            float B = -2.f * KLOG2E * li;
            e -= (float)npad * __builtin_amdgcn_exp2f(fmaf(B, t, (t * KLOG2E) * t));
        }
        float oa = a / e;
        out[rowbase + tid] = make_float2(li * cosf(oa), li * sinf(oa));
    }
}

// ---------------------------------------------------------------------------
extern "C" void kernel_launch(void* const* d_in, const int* in_sizes, int n_in,
                              void* d_out, int out_size, void* d_ws, size_t ws_size,
                              hipStream_t stream) {
    const float* x = (const float*)d_in[0];
    sofa_kernel<<<N / RPB, NT, 0, stream>>>(x, (float2*)d_out);
}